// Round 8
// baseline (107.360 us; speedup 1.0000x reference)
//
#include <hip/hip_runtime.h>

typedef _Float16 half8 __attribute__((ext_vector_type(8)));
typedef _Float16 half4 __attribute__((ext_vector_type(4)));
typedef float f32x4 __attribute__((ext_vector_type(4)));
typedef float f32x16 __attribute__((ext_vector_type(16)));
typedef unsigned u32x4 __attribute__((ext_vector_type(4)));

#define N_B 2
#define S_LEN 2048
#define NH 16
#define HD 64
#define DM 1024
#define LOG2E 1.44269504088896f

__device__ __forceinline__ void gload16(const void* g, void* l) {
    __builtin_amdgcn_global_load_lds(
        (const __attribute__((address_space(1))) unsigned int*)g,
        (__attribute__((address_space(3))) unsigned int*)l, 16, 0, 0);
}

__device__ __forceinline__ float fexp2(float x) {
    float r;
    asm("v_exp_f32 %0, %1" : "=v"(r) : "v"(x));
    return r;
}

// ---------------------------------------------------------------------------
// Fused prep (one launch): blocks [0,4096) regroup K -> f16 [n][h][s][d];
// [4096,5120) transpose V -> Vt f16 [n][h][d][s]; [5120,6144) cvt W -> f16.
// ---------------------------------------------------------------------------
__global__ __launch_bounds__(256) void k_prep(const float* __restrict__ K,
                                              const float* __restrict__ V,
                                              const float* __restrict__ Wo,
                                              _Float16* __restrict__ Kh,
                                              _Float16* __restrict__ Vt,
                                              _Float16* __restrict__ Wh) {
    __shared__ _Float16 tile[64][65];
    const int id = blockIdx.x;
    if (id < 4096) {                       // ---- K regroup
        int i = id * 256 + threadIdx.x;
        float4 v = ((const float4*)K)[i];
        int base = i * 4;
        int d = base & 63;
        int h = (base >> 6) & 15;
        int s = (base >> 10) & 2047;
        int n = base >> 21;
        size_t o = ((size_t)((n * NH + h) * S_LEN + s)) * HD + d;
        half4 hv = {(_Float16)v.x, (_Float16)v.y, (_Float16)v.z, (_Float16)v.w};
        *(half4*)(Kh + o) = hv;
    } else if (id < 5120) {                // ---- V transpose
        int b = id - 4096;
        int st = b & 31, h = (b >> 5) & 15, n = b >> 9;
        int c = threadIdx.x & 63, r0 = threadIdx.x >> 6;
#pragma unroll
        for (int i = 0; i < 16; ++i) {
            int r = i * 4 + r0;
            tile[r][c] = (_Float16)V[((size_t)(n * S_LEN) + st * 64 + r) * DM + h * HD + c];
        }
        __syncthreads();
#pragma unroll
        for (int i = 0; i < 16; ++i) {
            int d = i * 4 + r0;
            Vt[((size_t)((n * NH + h) * HD + d)) * S_LEN + st * 64 + c] = tile[c][d];
        }
    } else {                               // ---- W convert
        int i = (id - 5120) * 256 + threadIdx.x;
        float4 v = ((const float4*)Wo)[i];
        half4 hv = {(_Float16)v.x, (_Float16)v.y, (_Float16)v.z, (_Float16)v.w};
        *(half4*)(Wh + (size_t)i * 4) = hv;
    }
}

// ---------------------------------------------------------------------------
// Flash attention, 32x32 MFMA, 32 q-rows/wave, in-register P.
// Swapped QK^T: S^T = mfma(K,Q) -> lane owns q=lane&31; per lane 16 keys/block
// at crow(r,hi) = (r&3)+8*(r>>2)+4*hi. P repacked to A-fragment (k=8*hi+j)
// via pk-casts + shfl_xor(32) + cndmask (no LDS round trip).
// K/V LDS tiles staged exactly as the green R6 skeleton (gload16, inverse-
// swizzled source, __syncthreads full drain per tile, no DMA at endpgm).
// ---------------------------------------------------------------------------
__global__ __launch_bounds__(256) void k_attn(const float* __restrict__ Q,
                                              const _Float16* __restrict__ Kh,
                                              const _Float16* __restrict__ Vth,
                                              _Float16* __restrict__ Oatt) {
    __shared__ _Float16 KT[2][64 * 64];   // 16 KB
    __shared__ _Float16 VS[2][64 * 64];   // 16 KB

    // XCD swizzle (bijective on 512 = 8 * 64): 4 nh per XCD, 16 qt each
    const int id = blockIdx.x;
    const int xcd = id & 7;
    const int sl = id >> 3;              // 0..63
    const int nh = xcd + 8 * (sl >> 4);
    const int qt = sl & 15;              // q tile of 128

    const int tid = threadIdx.x;
    const int w = tid >> 6;
    const int lane = tid & 63;
    const int l31 = lane & 31;
    const int hi = lane >> 5;
    const int n = nh >> 4, h = nh & 15;

    const size_t head = (size_t)nh * S_LEN * HD;
    const char* Khead = (const char*)(Kh + head);
    const char* Vhead = (const char*)(Vth + head);

    // ---- Q fragments (B-frag: col q=l31, k=8hi+j per 16-d chunk), LOG2E-scaled
    const int qg = qt * 128 + w * 32 + l31;
    const float* qbase = Q + ((size_t)(n * S_LEN) + qg) * DM + h * HD;
    auto mkqf = [&](int c) -> half8 {
        float4 a = *(const float4*)(qbase + 16 * c + 8 * hi);
        float4 b = *(const float4*)(qbase + 16 * c + 8 * hi + 4);
        half8 r = {(_Float16)(a.x * LOG2E), (_Float16)(a.y * LOG2E),
                   (_Float16)(a.z * LOG2E), (_Float16)(a.w * LOG2E),
                   (_Float16)(b.x * LOG2E), (_Float16)(b.y * LOG2E),
                   (_Float16)(b.z * LOG2E), (_Float16)(b.w * LOG2E)};
        return r;
    };
    half8 qf0 = mkqf(0), qf1 = mkqf(1), qf2 = mkqf(2), qf3 = mkqf(3);

    f32x16 oacc0 = {}, oacc1 = {};
    float m_q = -1e30f, l_q = 0.f;       // per q=l31 (2x redundant over hi)

    // staging geometry: wave w stages 2 x 1KB slices of each 8KB tile
    const int rr = lane >> 3;
    const int cb = (lane & 7) * 16;
    const int gcb = cb ^ (rr << 4);      // inverse-swizzled global column

    auto STAGE = [&](int kt, int b) {
#pragma unroll
        for (int j = 0; j < 2; ++j) {
            int row = (w * 2 + j) * 8 + rr;
            gload16(Khead + ((size_t)(kt * 64 + row)) * 128 + gcb,
                    (char*)&KT[b][0] + (w * 2 + j) * 1024);
            gload16(Vhead + (size_t)row * 4096 + (size_t)kt * 128 + gcb,
                    (char*)&VS[b][0] + (w * 2 + j) * 1024);
        }
    };

    const int rmask = (l31 & 7) << 4;
    // fragment read: row = 32*blk + l31, 16B at d/key-offset 16*c + 8*hi
    auto ldF = [&](const char* lds, int blk, int c) -> half8 {
        int off = (32 * blk + l31) * 128 + ((32 * c + 16 * hi) ^ rmask);
        return *(const half8*)(lds + off);
    };

    auto pk2 = [&](float a, float b) -> unsigned {
        unsigned short ua = __builtin_bit_cast(unsigned short, (_Float16)a);
        unsigned short ub = __builtin_bit_cast(unsigned short, (_Float16)b);
        return (unsigned)ua | ((unsigned)ub << 16);
    };
    // P C-layout (keys (r&3)+8(r>>2)+4hi) -> A-frag (keys 8hi+j) for one 16-key chunk
    auto mkpa = [&](const f32x16& S, int rb) -> half8 {
        unsigned w0 = pk2(S[rb + 0], S[rb + 1]);
        unsigned w1 = pk2(S[rb + 2], S[rb + 3]);
        unsigned w2 = pk2(S[rb + 4], S[rb + 5]);
        unsigned w3 = pk2(S[rb + 6], S[rb + 7]);
        unsigned x0 = (unsigned)__shfl_xor((int)w0, 32);
        unsigned x1 = (unsigned)__shfl_xor((int)w1, 32);
        unsigned x2 = (unsigned)__shfl_xor((int)w2, 32);
        unsigned x3 = (unsigned)__shfl_xor((int)w3, 32);
        u32x4 t;
        t[0] = hi ? x2 : w0;   // keys 8hi+{0,1}
        t[1] = hi ? x3 : w1;   // keys 8hi+{2,3}
        t[2] = hi ? w2 : x0;   // keys 8hi+{4,5}
        t[3] = hi ? w3 : x1;   // keys 8hi+{6,7}
        return __builtin_bit_cast(half8, t);
    };

    auto BODY = [&](int kt, int buf, bool do_stage) {
        if (do_stage) STAGE(kt + 1, buf ^ 1);
        const char* ldsK = (const char*)&KT[buf][0];
        const char* ldsV = (const char*)&VS[buf][0];

        // ---- S^T = K Q^T : two 32-key blocks, d chained over 4 chunks
        f32x16 s0 = {}, s1 = {};
        s0 = __builtin_amdgcn_mfma_f32_32x32x16_f16(ldF(ldsK, 0, 0), qf0, s0, 0, 0, 0);
        s0 = __builtin_amdgcn_mfma_f32_32x32x16_f16(ldF(ldsK, 0, 1), qf1, s0, 0, 0, 0);
        s0 = __builtin_amdgcn_mfma_f32_32x32x16_f16(ldF(ldsK, 0, 2), qf2, s0, 0, 0, 0);
        s0 = __builtin_amdgcn_mfma_f32_32x32x16_f16(ldF(ldsK, 0, 3), qf3, s0, 0, 0, 0);
        s1 = __builtin_amdgcn_mfma_f32_32x32x16_f16(ldF(ldsK, 1, 0), qf0, s1, 0, 0, 0);
        s1 = __builtin_amdgcn_mfma_f32_32x32x16_f16(ldF(ldsK, 1, 1), qf1, s1, 0, 0, 0);
        s1 = __builtin_amdgcn_mfma_f32_32x32x16_f16(ldF(ldsK, 1, 2), qf2, s1, 0, 0, 0);
        s1 = __builtin_amdgcn_mfma_f32_32x32x16_f16(ldF(ldsK, 1, 3), qf3, s1, 0, 0, 0);

        // ---- lane-local online softmax (exp2 domain), defer-max THR=8
        float mx[16];
#pragma unroll
        for (int i = 0; i < 16; ++i) mx[i] = fmaxf(s0[i], s1[i]);
#pragma unroll
        for (int st = 8; st > 0; st >>= 1)
#pragma unroll
            for (int i = 0; i < 8; ++i)
                if (i < st) mx[i] = fmaxf(mx[i], mx[i + st]);
        float tm = fmaxf(mx[0], __shfl_xor(mx[0], 32));   // per-q max, all 64 keys
        if (!__all(tm <= m_q + 8.f)) {
            float mn = fmaxf(m_q, tm);
            float sc = fexp2(m_q - mn);
            m_q = mn;
            l_q *= sc;
            int scb = __builtin_bit_cast(int, sc);
#pragma unroll
            for (int r = 0; r < 16; ++r) {
                int qr = (r & 3) + 8 * (r >> 2) + 4 * hi;
                float s = __builtin_bit_cast(float, __builtin_amdgcn_ds_bpermute(4 * qr, scb));
                oacc0[r] *= s;
                oacc1[r] *= s;
            }
        }
        float rs = 0.f;
#pragma unroll
        for (int i = 0; i < 16; ++i) { float p = fexp2(s0[i] - m_q); s0[i] = p; rs += p; }
#pragma unroll
        for (int i = 0; i < 16; ++i) { float p = fexp2(s1[i] - m_q); s1[i] = p; rs += p; }
        rs += __shfl_xor(rs, 32);
        l_q += rs;

        // ---- P -> A-fragments (in-register)
        half8 pa0 = mkpa(s0, 0), pa1 = mkpa(s0, 8);
        half8 pa2 = mkpa(s1, 0), pa3 = mkpa(s1, 8);

        // ---- O += P V  (two 32-d blocks, keys chained over 4 chunks)
        oacc0 = __builtin_amdgcn_mfma_f32_32x32x16_f16(pa0, ldF(ldsV, 0, 0), oacc0, 0, 0, 0);
        oacc0 = __builtin_amdgcn_mfma_f32_32x32x16_f16(pa1, ldF(ldsV, 0, 1), oacc0, 0, 0, 0);
        oacc0 = __builtin_amdgcn_mfma_f32_32x32x16_f16(pa2, ldF(ldsV, 0, 2), oacc0, 0, 0, 0);
        oacc0 = __builtin_amdgcn_mfma_f32_32x32x16_f16(pa3, ldF(ldsV, 0, 3), oacc0, 0, 0, 0);
        oacc1 = __builtin_amdgcn_mfma_f32_32x32x16_f16(pa0, ldF(ldsV, 1, 0), oacc1, 0, 0, 0);
        oacc1 = __builtin_amdgcn_mfma_f32_32x32x16_f16(pa1, ldF(ldsV, 1, 1), oacc1, 0, 0, 0);
        oacc1 = __builtin_amdgcn_mfma_f32_32x32x16_f16(pa2, ldF(ldsV, 1, 2), oacc1, 0, 0, 0);
        oacc1 = __builtin_amdgcn_mfma_f32_32x32x16_f16(pa3, ldF(ldsV, 1, 3), oacc1, 0, 0, 0);

        if (do_stage) __syncthreads();   // full drain (vmcnt 0 + lgkmcnt 0) + barrier
    };

    STAGE(0, 0);
    __syncthreads();
    for (int t = 0; t < 31; ++t) BODY(t, t & 1, true);
    BODY(31, 1, false);   // no stage, no trailing barrier, no DMA at endpgm

    // ---- epilogue: Oatt[n][q][h*64+d] = oacc / l ----
    float rinv = 1.f / l_q;
    int rb = __builtin_bit_cast(int, rinv);
#pragma unroll
    for (int r = 0; r < 16; ++r) {
        int qr = (r & 3) + 8 * (r >> 2) + 4 * hi;
        float iv = __builtin_bit_cast(float, __builtin_amdgcn_ds_bpermute(4 * qr, rb));
        int qglob = qt * 128 + w * 32 + qr;
        size_t base = ((size_t)(n * S_LEN + qglob)) * DM + h * HD + l31;
        Oatt[base] = (_Float16)(oacc0[r] * iv);
        Oatt[base + 32] = (_Float16)(oacc1[r] * iv);
    }
}

// ---------------------------------------------------------------------------
// Projection GEMM, m97-style: 128x128 tile, BK=64, LDS double-buffered via
// gload16 (inverse-swizzled source, linear dest), 4 waves a 64x64 output.
// Grid 256 = 8 ot-strips x 32 mt; ot pinned per XCD (W strip L2-resident).
// ---------------------------------------------------------------------------
__global__ __launch_bounds__(256) void k_proj(const _Float16* __restrict__ A,
                                              const _Float16* __restrict__ W,
                                              const float* __restrict__ bias,
                                              float* __restrict__ out) {
    __shared__ _Float16 As[2][128 * 64];   // 16 KB each
    __shared__ _Float16 Ws[2][128 * 64];

    const int id = blockIdx.x;
    const int ot = id & 7;     // O strip of 128
    const int mt = id >> 3;    // M strip of 128 (0..31)
    const int tid = threadIdx.x;
    const int w = tid >> 6;
    const int lane = tid & 63;
    const int lr = lane & 15, lg = lane >> 4;
    const int wm = (w >> 1) * 64, wn = (w & 1) * 64;

    const int rr = lane >> 3;
    const int cb = (lane & 7) * 16;
    const int gcb = cb ^ (rr << 4);

    const char* Abase = (const char*)(A + (size_t)(mt * 128) * DM);
    const char* Wbase = (const char*)(W + (size_t)(ot * 128) * DM);

    auto STAGE = [&](int kt, int b) {
#pragma unroll
        for (int r = 0; r < 4; ++r) {
            int row = r * 32 + w * 8 + rr;
            gload16(Abase + (size_t)row * 2048 + kt * 128 + gcb,
                    (char*)&As[b][0] + (r * 32 + w * 8) * 128);
            gload16(Wbase + (size_t)row * 2048 + kt * 128 + gcb,
                    (char*)&Ws[b][0] + (r * 32 + w * 8) * 128);
        }
    };

    f32x4 zero = {0.f, 0.f, 0.f, 0.f};
    f32x4 acc[4][4];
#pragma unroll
    for (int mi = 0; mi < 4; ++mi)
#pragma unroll
        for (int ni = 0; ni < 4; ++ni) acc[mi][ni] = zero;

    auto COMPUTE = [&](int b) {
        const char* ldsA = (const char*)&As[b][0];
        const char* ldsW = (const char*)&Ws[b][0];
        half8 af[4][2], wf[4][2];
#pragma unroll
        for (int mi = 0; mi < 4; ++mi) {
            int row = wm + mi * 16 + lr;
            int sw = (row & 7) << 4;
            const char* p = ldsA + row * 128;
            af[mi][0] = *(const half8*)(p + ((lg * 16) ^ sw));
            af[mi][1] = *(const half8*)(p + ((64 + lg * 16) ^ sw));
        }
#pragma unroll
        for (int ni = 0; ni < 4; ++ni) {
            int row = wn + ni * 16 + lr;
            int sw = (row & 7) << 4;
            const char* p = ldsW + row * 128;
            wf[ni][0] = *(const half8*)(p + ((lg * 16) ^ sw));
            wf[ni][1] = *(const half8*)(p + ((64 + lg * 16) ^ sw));
        }
#pragma unroll
        for (int mi = 0; mi < 4; ++mi)
#pragma unroll
            for (int ni = 0; ni < 4; ++ni) {
                acc[mi][ni] = __builtin_amdgcn_mfma_f32_16x16x32_f16(af[mi][0], wf[ni][0], acc[mi][ni], 0, 0, 0);
                acc[mi][ni] = __builtin_amdgcn_mfma_f32_16x16x32_f16(af[mi][1], wf[ni][1], acc[mi][ni], 0, 0, 0);
            }
    };

    STAGE(0, 0);
    __syncthreads();
    for (int kt = 0; kt < 15; ++kt) {
        STAGE(kt + 1, (kt & 1) ^ 1);
        COMPUTE(kt & 1);
        __syncthreads();
    }
    COMPUTE(1);   // kt=15, no stage -> no DMA outstanding at endpgm

    // epilogue: C row = m (A dim), col = o (W dim)
#pragma unroll
    for (int ni = 0; ni < 4; ++ni) {
        int o = ot * 128 + wn + ni * 16 + lr;
        float b = bias[o];
#pragma unroll
        for (int mi = 0; mi < 4; ++mi)
#pragma unroll
            for (int i = 0; i < 4; ++i) {
                int m = mt * 128 + wm + mi * 16 + lg * 4 + i;
                out[(size_t)m * DM + o] = acc[mi][ni][i] + b;
            }
    }
}

// ---------------------------------------------------------------------------
extern "C" void kernel_launch(void* const* d_in, const int* in_sizes, int n_in,
                              void* d_out, int out_size, void* d_ws, size_t ws_size,
                              hipStream_t stream) {
    const float* Q = (const float*)d_in[0];
    const float* K = (const float*)d_in[1];
    const float* V = (const float*)d_in[2];
    const float* Wo = (const float*)d_in[3];
    const float* bo = (const float*)d_in[4];
    float* out = (float*)d_out;
    char* ws = (char*)d_ws;

    _Float16* Kh = (_Float16*)(ws);                     // 8 MB
    _Float16* Vt = (_Float16*)(ws + (8u << 20));        // 8 MB
    _Float16* Oatt = (_Float16*)(ws + (16u << 20));     // 8 MB
    _Float16* Wh = (_Float16*)(ws + (24u << 20));       // 2 MB

    k_prep<<<6144, 256, 0, stream>>>(K, V, Wo, Kh, Vt, Wh);
    k_attn<<<512, 256, 0, stream>>>(Q, Kh, Vt, Oatt);
    k_proj<<<256, 256, 0, stream>>>(Oatt, Wh, bo, out);
}

// Round 9
// 98.350 us; speedup vs baseline: 1.0916x; 1.0916x over previous
//
#include <hip/hip_runtime.h>

typedef _Float16 half8 __attribute__((ext_vector_type(8)));
typedef _Float16 half4 __attribute__((ext_vector_type(4)));
typedef float f32x4 __attribute__((ext_vector_type(4)));
typedef float f32x16 __attribute__((ext_vector_type(16)));
typedef unsigned u32x4 __attribute__((ext_vector_type(4)));

#define N_B 2
#define S_LEN 2048
#define NH 16
#define HD 64
#define DM 1024
#define LOG2E 1.44269504088896f

__device__ __forceinline__ void gload16(const void* g, void* l) {
    __builtin_amdgcn_global_load_lds(
        (const __attribute__((address_space(1))) unsigned int*)g,
        (__attribute__((address_space(3))) unsigned int*)l, 16, 0, 0);
}

__device__ __forceinline__ float fexp2(float x) {
    float r;
    asm("v_exp_f32 %0, %1" : "=v"(r) : "v"(x));
    return r;
}

// ---------------------------------------------------------------------------
// Fused prep (one launch): blocks [0,4096) regroup K -> f16 [n][h][s][d];
// [4096,5120) transpose V -> Vt f16 [n][h][d][s]; [5120,6144) cvt W -> f16.
// ---------------------------------------------------------------------------
__global__ __launch_bounds__(256) void k_prep(const float* __restrict__ K,
                                              const float* __restrict__ V,
                                              const float* __restrict__ Wo,
                                              _Float16* __restrict__ Kh,
                                              _Float16* __restrict__ Vt,
                                              _Float16* __restrict__ Wh) {
    __shared__ _Float16 tile[64][65];
    const int id = blockIdx.x;
    if (id < 4096) {                       // ---- K regroup
        int i = id * 256 + threadIdx.x;
        float4 v = ((const float4*)K)[i];
        int base = i * 4;
        int d = base & 63;
        int h = (base >> 6) & 15;
        int s = (base >> 10) & 2047;
        int n = base >> 21;
        size_t o = ((size_t)((n * NH + h) * S_LEN + s)) * HD + d;
        half4 hv = {(_Float16)v.x, (_Float16)v.y, (_Float16)v.z, (_Float16)v.w};
        *(half4*)(Kh + o) = hv;
    } else if (id < 5120) {                // ---- V transpose
        int b = id - 4096;
        int st = b & 31, h = (b >> 5) & 15, n = b >> 9;
        int c = threadIdx.x & 63, r0 = threadIdx.x >> 6;
#pragma unroll
        for (int i = 0; i < 16; ++i) {
            int r = i * 4 + r0;
            tile[r][c] = (_Float16)V[((size_t)(n * S_LEN) + st * 64 + r) * DM + h * HD + c];
        }
        __syncthreads();
#pragma unroll
        for (int i = 0; i < 16; ++i) {
            int d = i * 4 + r0;
            Vt[((size_t)((n * NH + h) * HD + d)) * S_LEN + st * 64 + c] = tile[c][d];
        }
    } else {                               // ---- W convert
        int i = (id - 5120) * 256 + threadIdx.x;
        float4 v = ((const float4*)Wo)[i];
        half4 hv = {(_Float16)v.x, (_Float16)v.y, (_Float16)v.z, (_Float16)v.w};
        *(half4*)(Wh + (size_t)i * 4) = hv;
    }
}

// ---------------------------------------------------------------------------
// Flash attention: 32x32 MFMA, in-register P, wave-level KV split.
// Block = 8 waves (512 thr), QBLK=128. Wave w: q-subtile (w&3), KV half
// (w>>2) of 1024 keys (16 tiles of 64). Per round both halves' K/V tiles
// are staged (32 KB, dbuf = 64 KB LDS). Epilogue merges wave-pair partials
// (m,l,O) via LDS in exp2 domain. Sync: __syncthreads 2-phase (full drain),
// no DMA outstanding at endpgm.
// ---------------------------------------------------------------------------
__global__ __launch_bounds__(512, 4) void k_attn(const float* __restrict__ Q,
                                                 const _Float16* __restrict__ Kh,
                                                 const _Float16* __restrict__ Vth,
                                                 _Float16* __restrict__ Oatt) {
    __shared__ char SB[65536];
    // [0,32768): K tiles  (b,hf) -> 8KB each ; [32768,65536): V tiles

    // XCD swizzle (bijective on 512 = 8 * 64): 4 nh per XCD, 16 qt each
    const int id = blockIdx.x;
    const int xcd = id & 7;
    const int sl = id >> 3;              // 0..63
    const int nh = xcd + 8 * (sl >> 4);
    const int qt = sl & 15;              // q tile of 128

    const int tid = threadIdx.x;
    const int w = tid >> 6;              // 0..7
    const int wq = w & 3;                // q-subtile
    const int hf = w >> 2;               // KV half
    const int lane = tid & 63;
    const int l31 = lane & 31;
    const int hi = lane >> 5;
    const int n = nh >> 4, h = nh & 15;

    const size_t head = (size_t)nh * S_LEN * HD;
    const char* Khead = (const char*)(Kh + head);
    const char* Vhead = (const char*)(Vth + head);

    // ---- Q fragments (B-frag: col q=l31, k=8hi+j per 16-d chunk), LOG2E-scaled
    const int qg = qt * 128 + wq * 32 + l31;
    const float* qbase = Q + ((size_t)(n * S_LEN) + qg) * DM + h * HD;
    auto mkqf = [&](int c) -> half8 {
        float4 a = *(const float4*)(qbase + 16 * c + 8 * hi);
        float4 b = *(const float4*)(qbase + 16 * c + 8 * hi + 4);
        half8 r = {(_Float16)(a.x * LOG2E), (_Float16)(a.y * LOG2E),
                   (_Float16)(a.z * LOG2E), (_Float16)(a.w * LOG2E),
                   (_Float16)(b.x * LOG2E), (_Float16)(b.y * LOG2E),
                   (_Float16)(b.z * LOG2E), (_Float16)(b.w * LOG2E)};
        return r;
    };
    half8 qf0 = mkqf(0), qf1 = mkqf(1), qf2 = mkqf(2), qf3 = mkqf(3);

    f32x16 oacc0 = {}, oacc1 = {};
    float m_q = -1e30f, l_q = 0.f;       // per q=l31 (2x redundant over hi)

    // staging geometry: wave w stages slices (w&3)*2+j of its half's tiles
    const int rr = lane >> 3;
    const int cb = (lane & 7) * 16;
    const int gcb = cb ^ (rr << 4);      // inverse-swizzled global column

    auto kbuf = [&](int b, int half) -> char* { return SB + (b * 2 + half) * 8192; };
    auto vbuf = [&](int b, int half) -> char* { return SB + 32768 + (b * 2 + half) * 8192; };

    auto STAGE = [&](int t, int b) {
#pragma unroll
        for (int j = 0; j < 2; ++j) {
            int slice = wq * 2 + j;            // 0..7
            int row = slice * 8 + rr;          // 0..63
            int key = hf * 1024 + t * 64 + row;
            gload16(Khead + (size_t)key * 128 + gcb, kbuf(b, hf) + slice * 1024);
            gload16(Vhead + (size_t)row * 4096 + hf * 2048 + t * 128 + gcb,
                    vbuf(b, hf) + slice * 1024);
        }
    };

    const int rmask = (l31 & 7) << 4;
    auto ldF = [&](const char* lds, int blk, int c) -> half8 {
        int off = (32 * blk + l31) * 128 + ((32 * c + 16 * hi) ^ rmask);
        return *(const half8*)(lds + off);
    };

    auto pk2 = [&](float a, float b) -> unsigned {
        unsigned short ua = __builtin_bit_cast(unsigned short, (_Float16)a);
        unsigned short ub = __builtin_bit_cast(unsigned short, (_Float16)b);
        return (unsigned)ua | ((unsigned)ub << 16);
    };
    auto mkpa = [&](const f32x16& S, int rb) -> half8 {
        unsigned w0 = pk2(S[rb + 0], S[rb + 1]);
        unsigned w1 = pk2(S[rb + 2], S[rb + 3]);
        unsigned w2 = pk2(S[rb + 4], S[rb + 5]);
        unsigned w3 = pk2(S[rb + 6], S[rb + 7]);
        unsigned x0 = (unsigned)__shfl_xor((int)w0, 32);
        unsigned x1 = (unsigned)__shfl_xor((int)w1, 32);
        unsigned x2 = (unsigned)__shfl_xor((int)w2, 32);
        unsigned x3 = (unsigned)__shfl_xor((int)w3, 32);
        u32x4 t;
        t[0] = hi ? x2 : w0;
        t[1] = hi ? x3 : w1;
        t[2] = hi ? w2 : x0;
        t[3] = hi ? w3 : x1;
        return __builtin_bit_cast(half8, t);
    };

    auto BODY = [&](int t, int buf, bool do_stage) {
        if (do_stage) STAGE(t + 1, buf ^ 1);
        const char* ldsK = kbuf(buf, hf);
        const char* ldsV = vbuf(buf, hf);

        // ---- S^T = K Q^T : two 32-key blocks, d chained over 4 chunks
        f32x16 s0 = {}, s1 = {};
        s0 = __builtin_amdgcn_mfma_f32_32x32x16_f16(ldF(ldsK, 0, 0), qf0, s0, 0, 0, 0);
        s0 = __builtin_amdgcn_mfma_f32_32x32x16_f16(ldF(ldsK, 0, 1), qf1, s0, 0, 0, 0);
        s0 = __builtin_amdgcn_mfma_f32_32x32x16_f16(ldF(ldsK, 0, 2), qf2, s0, 0, 0, 0);
        s0 = __builtin_amdgcn_mfma_f32_32x32x16_f16(ldF(ldsK, 0, 3), qf3, s0, 0, 0, 0);
        s1 = __builtin_amdgcn_mfma_f32_32x32x16_f16(ldF(ldsK, 1, 0), qf0, s1, 0, 0, 0);
        s1 = __builtin_amdgcn_mfma_f32_32x32x16_f16(ldF(ldsK, 1, 1), qf1, s1, 0, 0, 0);
        s1 = __builtin_amdgcn_mfma_f32_32x32x16_f16(ldF(ldsK, 1, 2), qf2, s1, 0, 0, 0);
        s1 = __builtin_amdgcn_mfma_f32_32x32x16_f16(ldF(ldsK, 1, 3), qf3, s1, 0, 0, 0);

        // ---- lane-local online softmax (exp2 domain), defer-max THR=8
        float mx[16];
#pragma unroll
        for (int i = 0; i < 16; ++i) mx[i] = fmaxf(s0[i], s1[i]);
#pragma unroll
        for (int st = 8; st > 0; st >>= 1)
#pragma unroll
            for (int i = 0; i < 8; ++i)
                if (i < st) mx[i] = fmaxf(mx[i], mx[i + st]);
        float tm = fmaxf(mx[0], __shfl_xor(mx[0], 32));
        if (!__all(tm <= m_q + 8.f)) {
            float mn = fmaxf(m_q, tm);
            float sc = fexp2(m_q - mn);
            m_q = mn;
            l_q *= sc;
            int scb = __builtin_bit_cast(int, sc);
#pragma unroll
            for (int r = 0; r < 16; ++r) {
                int qr = (r & 3) + 8 * (r >> 2) + 4 * hi;
                float s = __builtin_bit_cast(float, __builtin_amdgcn_ds_bpermute(4 * qr, scb));
                oacc0[r] *= s;
                oacc1[r] *= s;
            }
        }
        float rs = 0.f;
#pragma unroll
        for (int i = 0; i < 16; ++i) { float p = fexp2(s0[i] - m_q); s0[i] = p; rs += p; }
#pragma unroll
        for (int i = 0; i < 16; ++i) { float p = fexp2(s1[i] - m_q); s1[i] = p; rs += p; }
        rs += __shfl_xor(rs, 32);
        l_q += rs;

        // ---- P -> A-fragments (in-register)
        half8 pa0 = mkpa(s0, 0), pa1 = mkpa(s0, 8);
        half8 pa2 = mkpa(s1, 0), pa3 = mkpa(s1, 8);

        // ---- O += P V
        oacc0 = __builtin_amdgcn_mfma_f32_32x32x16_f16(pa0, ldF(ldsV, 0, 0), oacc0, 0, 0, 0);
        oacc0 = __builtin_amdgcn_mfma_f32_32x32x16_f16(pa1, ldF(ldsV, 0, 1), oacc0, 0, 0, 0);
        oacc0 = __builtin_amdgcn_mfma_f32_32x32x16_f16(pa2, ldF(ldsV, 0, 2), oacc0, 0, 0, 0);
        oacc0 = __builtin_amdgcn_mfma_f32_32x32x16_f16(pa3, ldF(ldsV, 0, 3), oacc0, 0, 0, 0);
        oacc1 = __builtin_amdgcn_mfma_f32_32x32x16_f16(pa0, ldF(ldsV, 1, 0), oacc1, 0, 0, 0);
        oacc1 = __builtin_amdgcn_mfma_f32_32x32x16_f16(pa1, ldF(ldsV, 1, 1), oacc1, 0, 0, 0);
        oacc1 = __builtin_amdgcn_mfma_f32_32x32x16_f16(pa2, ldF(ldsV, 1, 2), oacc1, 0, 0, 0);
        oacc1 = __builtin_amdgcn_mfma_f32_32x32x16_f16(pa3, ldF(ldsV, 1, 3), oacc1, 0, 0, 0);

        if (do_stage) __syncthreads();
    };

    STAGE(0, 0);
    __syncthreads();
    for (int t = 0; t < 15; ++t) BODY(t, t & 1, true);
    BODY(15, 1, false);   // peeled: no stage, no DMA at endpgm

    // ---- merge wave pairs (w <-> w+4) via LDS, exp2 domain ----
    __syncthreads();                       // all K/V reads done, SB reusable
    float* MRG = (float*)SB;               // 4 regions x 2176 f32 (8.5 KB)
    if (hf == 1) {
        float* B = MRG + wq * 2176;
        B[lane] = m_q;
        B[64 + lane] = l_q;
#pragma unroll
        for (int r = 0; r < 16; ++r) {
            B[128 + r * 64 + lane] = oacc0[r];
            B[1152 + r * 64 + lane] = oacc1[r];
        }
    }
    __syncthreads();
    if (hf == 0) {
        float* B = MRG + wq * 2176;
        float m1 = B[lane], l1 = B[64 + lane];
        float m = fmaxf(m_q, m1);
        float e0 = fexp2(m_q - m), e1 = fexp2(m1 - m);
        float linv = 1.f / (l_q * e0 + l1 * e1);
        int e0b = __builtin_bit_cast(int, e0);
        int e1b = __builtin_bit_cast(int, e1);
        int ivb = __builtin_bit_cast(int, linv);
#pragma unroll
        for (int r = 0; r < 16; ++r) {
            int qr = (r & 3) + 8 * (r >> 2) + 4 * hi;
            float s0f = __builtin_bit_cast(float, __builtin_amdgcn_ds_bpermute(4 * qr, e0b));
            float s1f = __builtin_bit_cast(float, __builtin_amdgcn_ds_bpermute(4 * qr, e1b));
            float iv = __builtin_bit_cast(float, __builtin_amdgcn_ds_bpermute(4 * qr, ivb));
            float o0 = (oacc0[r] * s0f + B[128 + r * 64 + lane] * s1f) * iv;
            float o1 = (oacc1[r] * s0f + B[1152 + r * 64 + lane] * s1f) * iv;
            int qglob = qt * 128 + wq * 32 + qr;
            size_t base = ((size_t)(n * S_LEN + qglob)) * DM + h * HD + l31;
            Oatt[base] = (_Float16)o0;
            Oatt[base + 32] = (_Float16)o1;
        }
    }
}

// ---------------------------------------------------------------------------
// Projection GEMM, m97-style: 128x128 tile, BK=64, LDS double-buffered via
// gload16 (inverse-swizzled source, linear dest), 4 waves a 64x64 output.
// Grid 256 = 8 ot-strips x 32 mt; ot pinned per XCD (W strip L2-resident).
// ---------------------------------------------------------------------------
__global__ __launch_bounds__(256) void k_proj(const _Float16* __restrict__ A,
                                              const _Float16* __restrict__ W,
                                              const float* __restrict__ bias,
                                              float* __restrict__ out) {
    __shared__ _Float16 As[2][128 * 64];   // 16 KB each
    __shared__ _Float16 Ws[2][128 * 64];

    const int id = blockIdx.x;
    const int ot = id & 7;     // O strip of 128
    const int mt = id >> 3;    // M strip of 128 (0..31)
    const int tid = threadIdx.x;
    const int w = tid >> 6;
    const int lane = tid & 63;
    const int lr = lane & 15, lg = lane >> 4;
    const int wm = (w >> 1) * 64, wn = (w & 1) * 64;

    const int rr = lane >> 3;
    const int cb = (lane & 7) * 16;
    const int gcb = cb ^ (rr << 4);

    const char* Abase = (const char*)(A + (size_t)(mt * 128) * DM);
    const char* Wbase = (const char*)(W + (size_t)(ot * 128) * DM);

    auto STAGE = [&](int kt, int b) {
#pragma unroll
        for (int r = 0; r < 4; ++r) {
            int row = r * 32 + w * 8 + rr;
            gload16(Abase + (size_t)row * 2048 + kt * 128 + gcb,
                    (char*)&As[b][0] + (r * 32 + w * 8) * 128);
            gload16(Wbase + (size_t)row * 2048 + kt * 128 + gcb,
                    (char*)&Ws[b][0] + (r * 32 + w * 8) * 128);
        }
    };

    f32x4 zero = {0.f, 0.f, 0.f, 0.f};
    f32x4 acc[4][4];
#pragma unroll
    for (int mi = 0; mi < 4; ++mi)
#pragma unroll
        for (int ni = 0; ni < 4; ++ni) acc[mi][ni] = zero;

    auto COMPUTE = [&](int b) {
        const char* ldsA = (const char*)&As[b][0];
        const char* ldsW = (const char*)&Ws[b][0];
        half8 af[4][2], wf[4][2];
#pragma unroll
        for (int mi = 0; mi < 4; ++mi) {
            int row = wm + mi * 16 + lr;
            int sw = (row & 7) << 4;
            const char* p = ldsA + row * 128;
            af[mi][0] = *(const half8*)(p + ((lg * 16) ^ sw));
            af[mi][1] = *(const half8*)(p + ((64 + lg * 16) ^ sw));
        }
#pragma unroll
        for (int ni = 0; ni < 4; ++ni) {
            int row = wn + ni * 16 + lr;
            int sw = (row & 7) << 4;
            const char* p = ldsW + row * 128;
            wf[ni][0] = *(const half8*)(p + ((lg * 16) ^ sw));
            wf[ni][1] = *(const half8*)(p + ((64 + lg * 16) ^ sw));
        }
#pragma unroll
        for (int mi = 0; mi < 4; ++mi)
#pragma unroll
            for (int ni = 0; ni < 4; ++ni) {
                acc[mi][ni] = __builtin_amdgcn_mfma_f32_16x16x32_f16(af[mi][0], wf[ni][0], acc[mi][ni], 0, 0, 0);
                acc[mi][ni] = __builtin_amdgcn_mfma_f32_16x16x32_f16(af[mi][1], wf[ni][1], acc[mi][ni], 0, 0, 0);
            }
    };

    STAGE(0, 0);
    __syncthreads();
    for (int kt = 0; kt < 15; ++kt) {
        STAGE(kt + 1, (kt & 1) ^ 1);
        COMPUTE(kt & 1);
        __syncthreads();
    }
    COMPUTE(1);   // kt=15, no stage -> no DMA outstanding at endpgm

    // epilogue: C row = m (A dim), col = o (W dim)
#pragma unroll
    for (int ni = 0; ni < 4; ++ni) {
        int o = ot * 128 + wn + ni * 16 + lr;
        float b = bias[o];
#pragma unroll
        for (int mi = 0; mi < 4; ++mi)
#pragma unroll
            for (int i = 0; i < 4; ++i) {
                int m = mt * 128 + wm + mi * 16 + lg * 4 + i;
                out[(size_t)m * DM + o] = acc[mi][ni][i] + b;
            }
    }
}

// ---------------------------------------------------------------------------
extern "C" void kernel_launch(void* const* d_in, const int* in_sizes, int n_in,
                              void* d_out, int out_size, void* d_ws, size_t ws_size,
                              hipStream_t stream) {
    const float* Q = (const float*)d_in[0];
    const float* K = (const float*)d_in[1];
    const float* V = (const float*)d_in[2];
    const float* Wo = (const float*)d_in[3];
    const float* bo = (const float*)d_in[4];
    float* out = (float*)d_out;
    char* ws = (char*)d_ws;

    _Float16* Kh = (_Float16*)(ws);                     // 8 MB
    _Float16* Vt = (_Float16*)(ws + (8u << 20));        // 8 MB
    _Float16* Oatt = (_Float16*)(ws + (16u << 20));     // 8 MB
    _Float16* Wh = (_Float16*)(ws + (24u << 20));       // 2 MB

    k_prep<<<6144, 256, 0, stream>>>(K, V, Wo, Kh, Vt, Wh);
    k_attn<<<512, 512, 0, stream>>>(Q, Kh, Vt, Oatt);
    k_proj<<<256, 256, 0, stream>>>(Oatt, Wh, bo, out);
}